// Round 18
// baseline (77.437 us; speedup 1.0000x reference)
//
#include <hip/hip_runtime.h>

#define S_LEN 4096
#define D_IN 256
#define D_OUT 64
#define BATCH 4
#define BQ 256
#define NQT (S_LEN / BQ)   // 16 q-tiles per batch

typedef short bf16x8 __attribute__((ext_vector_type(8)));
typedef float f32x4 __attribute__((ext_vector_type(4)));

union L16 { int4 i; bf16x8 s; ushort u[8]; };
union U8  { uint2 d; ushort u[4]; };

// byte offset into a [rows][128B] LDS tile (8x 16B chunks per row),
// XOR-swizzled per guide G4: chunk ^= (row & 7)
#define SWZ(row, chunk) (((row) << 7) + ((((chunk) ^ ((row) & 7))) << 4))

// 0.125 (1/sqrt(64)) * log2(e): scores come out of QK^T already in log2 units
#define QSCALE 0.1803368801111137f

__device__ inline ushort f2bf(float x) {           // RNE
    unsigned u = __builtin_bit_cast(unsigned, x);
    u += 0x7FFFu + ((u >> 16) & 1u);
    return (ushort)(u >> 16);
}
__device__ inline ushort f2bf_t(float x) {         // truncate (P only, P bounded)
    return (ushort)(__builtin_bit_cast(unsigned, x) >> 16);
}
__device__ inline float bf2f(ushort h) {
    return __builtin_bit_cast(float, (unsigned)h << 16);
}

// ---------------- W transpose+cast: Wt[3][64 n][256 k] bf16 = W[k][n] -------
__global__ __launch_bounds__(256) void wsplit_kernel(
    const float* __restrict__ wq, const float* __restrict__ wk, const float* __restrict__ wv,
    ushort* __restrict__ Wt)
{
    const float* W = (blockIdx.y == 0) ? wq : (blockIdx.y == 1) ? wk : wv;
    __shared__ float Ws[64][68];
    const int t  = threadIdx.x;
    const int k0 = blockIdx.x * 64;
#pragma unroll
    for (int i = 0; i < 4; ++i) {
        int idx = t + i * 256;                 // 0..1023
        int r = idx >> 4, c4 = (idx & 15) * 4;
        *reinterpret_cast<float4*>(&Ws[r][c4]) =
            *reinterpret_cast<const float4*>(&W[(size_t)(k0 + r) * 64 + c4]);
    }
    __syncthreads();
    const int n = t >> 2, kc = t & 3;
    ushort h[16];
#pragma unroll
    for (int i = 0; i < 16; ++i) h[i] = f2bf(Ws[kc * 16 + i][n]);
    ushort* dst = Wt + ((size_t)blockIdx.y * 64 + n) * 256 + k0 + kc * 16;
    *reinterpret_cast<int4*>(dst)     = *reinterpret_cast<int4*>(h);
    *reinterpret_cast<int4*>(dst + 8) = *reinterpret_cast<int4*>(h + 8);
}

// ---------------- projection via MFMA (X bf16 single, W bf16), no staging ---
// Q output is pre-scaled by QSCALE so attention scores land in log2 domain.
__global__ __launch_bounds__(256) void proj_kernel(
    const float* __restrict__ Xq, const float* __restrict__ Xk, const float* __restrict__ Xv,
    const ushort* __restrict__ Wt,
    ushort* __restrict__ Qb, ushort* __restrict__ Kb, ushort* __restrict__ Vtb)
{
    const float* X = (blockIdx.y == 0) ? Xq : (blockIdx.y == 1) ? Xk : Xv;
    const ushort* Wtp = Wt + (size_t)blockIdx.y * 64 * 256;

    __shared__ __align__(16) ushort Ob[64][64];     // output bounce (8 KiB)

    const int t    = threadIdx.x;
    const int lane = t & 63;
    const int w    = t >> 6;
    const int n    = lane & 15;
    const int g    = lane >> 4;
    const int row0 = blockIdx.x * 64;

    const float* xrow = X + (size_t)(row0 + 16 * w + n) * D_IN;

    f32x4 acc[4];
    const f32x4 zero4 = {0.f, 0.f, 0.f, 0.f};
#pragma unroll
    for (int nt = 0; nt < 4; ++nt) acc[nt] = zero4;

#pragma unroll
    for (int kt = 0; kt < 8; ++kt) {
        const float4 c0 = *reinterpret_cast<const float4*>(xrow + kt * 32 + 8 * g);
        const float4 c1 = *reinterpret_cast<const float4*>(xrow + kt * 32 + 8 * g + 4);
        L16 wb[4];
#pragma unroll
        for (int nt = 0; nt < 4; ++nt)
            wb[nt].i = *reinterpret_cast<const int4*>(
                &Wtp[(size_t)(16 * nt + n) * 256 + kt * 32 + 8 * g]);

        const float xv[8] = {c0.x, c0.y, c0.z, c0.w, c1.x, c1.y, c1.z, c1.w};
        L16 xh;
#pragma unroll
        for (int i = 0; i < 8; ++i) xh.u[i] = f2bf(xv[i]);
#pragma unroll
        for (int nt = 0; nt < 4; ++nt)
            acc[nt] = __builtin_amdgcn_mfma_f32_16x16x32_bf16(xh.s, wb[nt].s, acc[nt], 0, 0, 0);
    }

    // epilogue: bounce through LDS for coalesced bf16 stores (V transposed)
    const bool isV = (blockIdx.y == 2);
    const float oscale = (blockIdx.y == 0) ? QSCALE : 1.0f;
#pragma unroll
    for (int j = 0; j < 4; ++j) {
#pragma unroll
        for (int nt = 0; nt < 4; ++nt) {
            ushort h = f2bf(acc[nt][j] * oscale);
            int r = 16 * w + 4 * g + j;     // m-row in block
            int c = 16 * nt + n;            // output column
            if (isV) Ob[c][r] = h; else Ob[r][c] = h;
        }
    }
    __syncthreads();
    const int b  = row0 >> 12;
    const int s0 = row0 & 4095;
#pragma unroll
    for (int i = 0; i < 2; ++i) {
        int idx = t + i * 256;              // 0..511
        int r = idx >> 3, c8 = (idx & 7) * 8;
        int4 v = *reinterpret_cast<const int4*>(&Ob[r][c8]);
        if (blockIdx.y == 0)
            *reinterpret_cast<int4*>(&Qb[(size_t)(row0 + r) * 64 + c8]) = v;
        else if (blockIdx.y == 1)
            *reinterpret_cast<int4*>(&Kb[(size_t)(row0 + r) * 64 + c8]) = v;
        else
            *reinterpret_cast<int4*>(&Vtb[((size_t)b * 64 + r) * S_LEN + s0 + c8]) = v;
    }
}

// ---------------- causal flash attention, swapped-QK bf16 MFMA, split-K -----
// BQ=256: 8 waves (512 thr) x 32 q-rows each; double-buffered K/V LDS, one
// barrier per tile; shuffle-free softmax. NEW: fused PV for both h-groups —
// shared bv fragment loads, single 16-MFMA PV cluster per tile.
__global__ __launch_bounds__(512) void attn_kernel(
    const ushort* __restrict__ Q, const ushort* __restrict__ K,
    const ushort* __restrict__ Vt, float* __restrict__ O,
    ushort* __restrict__ Opart, float* __restrict__ Mpart, float* __restrict__ Lpart,
    int chunk_keys, int NCH, int lr4q, int Llive)
{
    __shared__ __align__(16) ushort Ks[2][64 * 64];    // K tiles, swizzled (2x8KB)
    __shared__ __align__(16) ushort Vs[2][64 * 64];    // V^T tiles, swizzled (2x8KB)
    __shared__ __align__(16) ushort Ps[8 * 16 * 64];   // per-wave P (2KB/wave, 16KB)

    const int Rq = 1 << lr4q;                    // chunk size in 256-row q-tile units

    // flat work item, chunk-major: off(c) = NQT*c - Rq*c*(c-1)/2
    const int b = blockIdx.x & 3;
    const int f = blockIdx.x >> 2;               // 0..Llive-1
    int c = 0;
    while (NQT * (c + 1) - ((Rq * (c + 1) * c) >> 1) <= f) ++c;   // <=16 iters
    const int off  = NQT * c - ((Rq * c * (c - 1)) >> 1);
    const int qt   = (NQT - 1) - (f - off);      // descending within chunk (LPT)
    const int ch   = c;
    const int q0   = qt * BQ;
    const int c0   = ch * chunk_keys;
    const int nchq = (qt >> lr4q) + 1;           // live chunks for this q-tile

    const int t    = threadIdx.x;
    const int lane = t & 63;
    const int w    = t >> 6;                     // 0..7
    const int n    = lane & 15;
    const int g    = lane >> 4;

    const int kend = (c0 + chunk_keys < q0 + BQ) ? c0 + chunk_keys : q0 + BQ;
    const int kt0  = c0 >> 6;
    const int kt1  = (kend + 63) >> 6;

    const ushort* Qp = Q  + (size_t)b * S_LEN * 64;
    const ushort* Kp = K  + (size_t)b * S_LEN * 64;
    const ushort* Vp = Vt + (size_t)b * 64 * S_LEN;

    char* PsB = (char*)Ps + w * 2048;

    const int wqmin = q0 + 32 * w;
    const int wqmax = wqmin + 31;

    // Q B-frags for both 16-col groups (col n of group h -> q-row wqmin+16h+n)
    L16 aq[2][2];
#pragma unroll
    for (int h = 0; h < 2; ++h) {
        const size_t qr = (size_t)(wqmin + 16 * h + n) * 64;
        aq[h][0].i = *reinterpret_cast<const int4*>(&Qp[qr + 8 * g]);
        aq[h][1].i = *reinterpret_cast<const int4*>(&Qp[qr + 32 + 8 * g]);
    }

    // all-ones A-frag for the MFMA row-sum (bf16 1.0 = 0x3F80)
    L16 ones;
    ones.i = make_int4(0x3F803F80, 0x3F803F80, 0x3F803F80, 0x3F803F80);

    f32x4 oacc[2][4];                            // oacc[h][nt][j] = O[qrow_h][16nt+4g+j]
    const f32x4 zero4 = {0.f, 0.f, 0.f, 0.f};
#pragma unroll
    for (int h = 0; h < 2; ++h)
#pragma unroll
        for (int nt = 0; nt < 4; ++nt) oacc[h][nt] = zero4;
    float mreg[2] = {-1e30f, -1e30f}, lreg[2] = {0.f, 0.f};

    const int srow = t >> 3, sc = t & 7;         // 512 thr: one row each (0..63)

    auto load_tile = [&](int4& kr, int4& vr, int kt_) {
        const int kk0 = kt_ << 6;
        kr = *reinterpret_cast<const int4*>(&Kp[(size_t)(kk0 + srow) * 64 + sc * 8]);
        vr = *reinterpret_cast<const int4*>(&Vp[(size_t)srow * S_LEN + kk0 + sc * 8]);
    };
    auto store_tile = [&](int buf, const int4& kr, const int4& vr) {
        char* kb = (char*)Ks + buf * 8192;
        char* vb = (char*)Vs + buf * 8192;
        *reinterpret_cast<int4*>(kb + SWZ(srow, sc)) = kr;
        *reinterpret_cast<int4*>(vb + SWZ(srow, sc)) = vr;
    };

    // prologue: stage tile kt0 into buf0; preload tile kt0+1 into regs
    int4 kv, vv;
    load_tile(kv, vv, kt0);
    store_tile(0, kv, vv);
    if (kt0 + 1 < kt1) load_tile(kv, vv, kt0 + 1);
    __syncthreads();

    int cur = 0;
    for (int kt = kt0; kt < kt1; ++kt) {
        const int k0 = kt << 6;
        // stage tile kt+1 into the other buffer; issue loads for kt+2
        if (kt + 1 < kt1) {
            store_tile(cur ^ 1, kv, vv);
            if (kt + 2 < kt1) load_tile(kv, vv, kt + 2);
        }

        if (k0 <= wqmax) {                       // compute (masked waves skip)
            char* KsB = (char*)Ks + cur * 8192;
            char* VsB = (char*)Vs + cur * 8192;

            // ---- QK^T swapped: A=K, B=Q. Lane holds S[key=k0+16t4+4g+j][qrow_h]
            f32x4 cS[2][4];
            __builtin_amdgcn_s_setprio(1);
#pragma unroll
            for (int t4 = 0; t4 < 4; ++t4) {
                L16 k0f, k1f;
                k0f.i = *reinterpret_cast<const int4*>(KsB + SWZ(16 * t4 + n, g));
                k1f.i = *reinterpret_cast<const int4*>(KsB + SWZ(16 * t4 + n, 4 + g));
#pragma unroll
                for (int h = 0; h < 2; ++h) {
                    f32x4 z = zero4;
                    z          = __builtin_amdgcn_mfma_f32_16x16x32_bf16(k0f.s, aq[h][0].s, z, 0, 0, 0);
                    cS[h][t4]  = __builtin_amdgcn_mfma_f32_16x16x32_bf16(k1f.s, aq[h][1].s, z, 0, 0, 0);
                }
            }
            __builtin_amdgcn_s_setprio(0);

            // ---- per group: mask + softmax + P-store + pa load (P buf reused)
            L16 pa[2][2];
#pragma unroll
            for (int h = 0; h < 2; ++h) {
                const int qrow = wqmin + 16 * h + n;
                float sc4[4][4];
#pragma unroll
                for (int t4 = 0; t4 < 4; ++t4)
#pragma unroll
                    for (int j = 0; j < 4; ++j) sc4[t4][j] = cS[h][t4][j];
                if (k0 + 63 > qrow) {
                    const int kb = k0 + 4 * g;
#pragma unroll
                    for (int t4 = 0; t4 < 4; ++t4)
#pragma unroll
                        for (int j = 0; j < 4; ++j)
                            if (kb + 16 * t4 + j > qrow) sc4[t4][j] = -1e30f;
                }

                // per-lane max of this lane's 16 scores (no cross-lane yet)
                float m0 = fmaxf(fmaxf(sc4[0][0], sc4[0][1]), fmaxf(sc4[0][2], sc4[0][3]));
                float m1 = fmaxf(fmaxf(sc4[1][0], sc4[1][1]), fmaxf(sc4[1][2], sc4[1][3]));
                float m2 = fmaxf(fmaxf(sc4[2][0], sc4[2][1]), fmaxf(sc4[2][2], sc4[2][3]));
                float m3 = fmaxf(fmaxf(sc4[3][0], sc4[3][1]), fmaxf(sc4[3][2], sc4[3][3]));
                const float lmax = fmaxf(fmaxf(m0, m1), fmaxf(m2, m3));

                // defer-max: full cross-lane reduce ONLY when a row grew > 8
                if (__any(lmax > mreg[h] + 8.f)) {
                    float mx = lmax;
                    mx = fmaxf(mx, __shfl_xor(mx, 16, 64));
                    mx = fmaxf(mx, __shfl_xor(mx, 32, 64));
                    const float mnew  = fmaxf(mreg[h], mx);
                    const float alpha = exp2f(mreg[h] - mnew);
                    mreg[h] = mnew;
                    lreg[h] *= alpha;
#pragma unroll
                    for (int nt = 0; nt < 4; ++nt)
#pragma unroll
                        for (int j = 0; j < 4; ++j) oacc[h][nt][j] *= alpha;
                }

#pragma unroll
                for (int t4 = 0; t4 < 4; ++t4) {
                    U8 pw;
#pragma unroll
                    for (int j = 0; j < 4; ++j)
                        pw.u[j] = f2bf_t(exp2f(sc4[t4][j] - mreg[h]));
                    *reinterpret_cast<uint2*>(PsB + SWZ(n, 2 * t4 + (g >> 1)) + 8 * (g & 1)) = pw.d;
                }
                // drain this h's P writes, pull its A-frags into regs, l-sum
                asm volatile("s_waitcnt lgkmcnt(0)" ::: "memory");
                pa[h][0].i = *reinterpret_cast<const int4*>(PsB + SWZ(n, g));
                pa[h][1].i = *reinterpret_cast<const int4*>(PsB + SWZ(n, 4 + g));
                f32x4 ls = zero4;
                ls = __builtin_amdgcn_mfma_f32_16x16x32_bf16(ones.s, pa[h][0].s, ls, 0, 0, 0);
                ls = __builtin_amdgcn_mfma_f32_16x16x32_bf16(ones.s, pa[h][1].s, ls, 0, 0, 0);
                lreg[h] += ls[0];                // all D-rows equal the column sum
            }

            // ---- fused PV for both h: shared bv loads, one 16-MFMA cluster
            __builtin_amdgcn_s_setprio(1);
#pragma unroll
            for (int nt = 0; nt < 4; ++nt) {
                L16 bv0, bv1;
                bv0.i = *reinterpret_cast<const int4*>(VsB + SWZ(16 * nt + n, g));
                bv1.i = *reinterpret_cast<const int4*>(VsB + SWZ(16 * nt + n, 4 + g));
                oacc[0][nt] = __builtin_amdgcn_mfma_f32_16x16x32_bf16(bv0.s, pa[0][0].s, oacc[0][nt], 0, 0, 0);
                oacc[0][nt] = __builtin_amdgcn_mfma_f32_16x16x32_bf16(bv1.s, pa[0][1].s, oacc[0][nt], 0, 0, 0);
                oacc[1][nt] = __builtin_amdgcn_mfma_f32_16x16x32_bf16(bv0.s, pa[1][0].s, oacc[1][nt], 0, 0, 0);
                oacc[1][nt] = __builtin_amdgcn_mfma_f32_16x16x32_bf16(bv1.s, pa[1][1].s, oacc[1][nt], 0, 0, 0);
            }
            __builtin_amdgcn_s_setprio(0);
        }
        __syncthreads();                         // one barrier per tile
        cur ^= 1;
    }

    if (nchq == 1) {
        // direct normalized write (qt < Rq), scattered 4B stores
#pragma unroll
        for (int h = 0; h < 2; ++h) {
            const float inv = 1.f / lreg[h];
            float* orow = O + ((size_t)b * S_LEN + wqmin + 16 * h + n) * 64;
#pragma unroll
            for (int nt = 0; nt < 4; ++nt)
#pragma unroll
                for (int j = 0; j < 4; ++j)
                    orow[16 * nt + 4 * g + j] = oacc[h][nt][j] * inv;
        }
    } else {
        // bf16 partials in swizzled byte order (reduce de-swizzles), per h
        const size_t slot = (size_t)((qt << 2) | b) * NCH + ch;
#pragma unroll
        for (int h = 0; h < 2; ++h) {
#pragma unroll
            for (int nt = 0; nt < 4; ++nt) {
                U8 pw;
#pragma unroll
                for (int j = 0; j < 4; ++j) pw.u[j] = f2bf(oacc[h][nt][j]);
                *reinterpret_cast<uint2*>(PsB + SWZ(n, 2 * nt + (g >> 1)) + 8 * (g & 1)) = pw.d;
            }
            asm volatile("s_waitcnt lgkmcnt(0)" ::: "memory");
            ushort* dst = Opart + slot * (BQ * 64) + w * 2048 + h * 1024;
#pragma unroll
            for (int i = 0; i < 2; ++i) {
                int ii = i * 64 + lane;
                *reinterpret_cast<int4*>(dst + ii * 8) =
                    *reinterpret_cast<const int4*>((const char*)PsB + ii * 16);
            }
        }
        if (g == 0) {
#pragma unroll
            for (int h = 0; h < 2; ++h) {
                Mpart[slot * BQ + 32 * w + 16 * h + n] = mreg[h];
                Lpart[slot * BQ + 32 * w + 16 * h + n] = lreg[h];
            }
        }
    }
}

// ---------------- split-K combine (bf16 partials, log2-domain m) ------------
// 8 blocks per (b,qt): seg = 32-row segment. 8 threads/row x 8 floats.
__global__ __launch_bounds__(256) void reduce_kernel(
    const ushort* __restrict__ Opart, const float* __restrict__ Mpart,
    const float* __restrict__ Lpart, float* __restrict__ O,
    int NCH, int chunk_keys)
{
    const int bx  = blockIdx.x >> 3;     // (qt<<2)|b
    const int seg = blockIdx.x & 7;      // 32-row segment of the 256-row q-tile
    const int b   = bx & 3;
    const int qt  = bx >> 2;
    const int q0  = qt * BQ;
    const int nch = (q0 + BQ + chunk_keys - 1) / chunk_keys;
    if (nch <= 1) return;               // attn wrote O directly

    const int t    = threadIdx.x;
    const int row  = seg * 32 + (t >> 3);   // 0..255
    const int c8   = t & 7;                 // 16B chunk within the row
    const int wv   = row >> 5, rl = row & 31;
    const int cswz = (c8 ^ (rl & 7)) << 4;  // de-swizzle

    const size_t mbase = (size_t)bx * NCH * BQ + row;
    float mmax = -1e30f;
#pragma unroll 4
    for (int ch = 0; ch < nch; ++ch)
        mmax = fmaxf(mmax, Mpart[mbase + (size_t)ch * BQ]);

    float ltot = 0.f;
    float acc[8];
#pragma unroll
    for (int i = 0; i < 8; ++i) acc[i] = 0.f;

#pragma unroll 4
    for (int ch = 0; ch < nch; ++ch) {
        const float wgt = exp2f(Mpart[mbase + (size_t)ch * BQ] - mmax);
        ltot += wgt * Lpart[mbase + (size_t)ch * BQ];
        const char* ob = (const char*)(Opart + ((size_t)bx * NCH + ch) * (BQ * 64))
                         + wv * 4096 + rl * 128 + cswz;
        L16 v;
        v.i = *reinterpret_cast<const int4*>(ob);
#pragma unroll
        for (int i = 0; i < 8; ++i) acc[i] += wgt * bf2f(v.u[i]);
    }
    const float inv = 1.f / ltot;
    float* dst = O + ((size_t)b * S_LEN + q0 + row) * 64 + c8 * 8;
#pragma unroll
    for (int i = 0; i < 2; ++i) {
        float4 o = make_float4(acc[4 * i] * inv, acc[4 * i + 1] * inv,
                               acc[4 * i + 2] * inv, acc[4 * i + 3] * inv);
        *reinterpret_cast<float4*>(dst + i * 4) = o;
    }
}

extern "C" void kernel_launch(void* const* d_in, const int* in_sizes, int n_in,
                              void* d_out, int out_size, void* d_ws, size_t ws_size,
                              hipStream_t stream) {
    // setup_inputs() order: keys-X, values-X, queries-X, wq, wk, wv
    const float* Xk = (const float*)d_in[0];
    const float* Xv = (const float*)d_in[1];
    const float* Xq = (const float*)d_in[2];
    const float* wq = (const float*)d_in[3];
    const float* wk = (const float*)d_in[4];
    const float* wv = (const float*)d_in[5];
    float* out = (float*)d_out;

    const size_t NEL = (size_t)BATCH * S_LEN * D_OUT;   // 1,048,576
    ushort* Qb  = (ushort*)d_ws;
    ushort* Kb  = Qb + NEL;
    ushort* Vtb = Kb + NEL;
    const size_t base_bytes = 3 * NEL * sizeof(ushort);               // 6,291,456
    const size_t per_nch    = (size_t)BATCH * NQT *
                              (BQ * 64 * sizeof(ushort) + 2 * BQ * sizeof(float));

    int NCH = 1;
    if      (ws_size >= base_bytes + 16 * per_nch) NCH = 16;
    else if (ws_size >= base_bytes +  8 * per_nch) NCH = 8;
    else if (ws_size >= base_bytes +  4 * per_nch) NCH = 4;
    else if (ws_size >= base_bytes +  2 * per_nch) NCH = 2;
    const int chunk_keys = S_LEN / NCH;                 // NCH=16 -> 256 = BQ
    const int Rq = chunk_keys / BQ;                     // chunk in 256-row q-tiles
    int lr4q = 0; while ((1 << lr4q) < Rq) ++lr4q;      // log2(Rq)
    const int Llive = NCH * NQT - Rq * ((NCH * (NCH - 1)) >> 1);

    ushort* Wt    = (ushort*)((char*)d_ws + base_bytes);   // aliases Opart
    ushort* Opart = (ushort*)((char*)d_ws + base_bytes);
    float*  Mpart = (float*)((char*)d_ws + base_bytes +
                             (size_t)BATCH * NQT * NCH * BQ * 64 * sizeof(ushort));
    float*  Lpart = Mpart + (size_t)BATCH * NQT * NCH * BQ;

    wsplit_kernel<<<dim3(4, 3), 256, 0, stream>>>(wq, wk, wv, Wt);

    proj_kernel<<<dim3(BATCH * S_LEN / 64, 3), 256, 0, stream>>>(
        Xq, Xk, Xv, Wt, Qb, Kb, Vtb);

    attn_kernel<<<4 * Llive, 512, 0, stream>>>(Qb, Kb, Vtb, out, Opart, Mpart, Lpart,
                                               chunk_keys, NCH, lr4q, Llive);
    if (NCH > 1)
        reduce_kernel<<<BATCH * NQT * 8, 256, 0, stream>>>(Opart, Mpart, Lpart, out,
                                                           NCH, chunk_keys);
}

// Round 19
// 67.250 us; speedup vs baseline: 1.1515x; 1.1515x over previous
//
#include <hip/hip_runtime.h>

#define S_LEN 4096
#define D_IN 256
#define D_OUT 64
#define BATCH 4
#define BQ 256
#define NQT (S_LEN / BQ)   // 16 q-tiles per batch

typedef short bf16x8 __attribute__((ext_vector_type(8)));
typedef float f32x4 __attribute__((ext_vector_type(4)));

union L16 { int4 i; bf16x8 s; ushort u[8]; };
union U8  { uint2 d; ushort u[4]; };

// byte offset into a [rows][128B] LDS tile (8x 16B chunks per row),
// XOR-swizzled per guide G4: chunk ^= (row & 7)
#define SWZ(row, chunk) (((row) << 7) + ((((chunk) ^ ((row) & 7))) << 4))

// 0.125 (1/sqrt(64)) * log2(e): scores come out of QK^T already in log2 units
#define QSCALE 0.1803368801111137f

__device__ inline ushort f2bf(float x) {           // RNE
    unsigned u = __builtin_bit_cast(unsigned, x);
    u += 0x7FFFu + ((u >> 16) & 1u);
    return (ushort)(u >> 16);
}
__device__ inline ushort f2bf_t(float x) {         // truncate (P only, P bounded)
    return (ushort)(__builtin_bit_cast(unsigned, x) >> 16);
}
__device__ inline float bf2f(ushort h) {
    return __builtin_bit_cast(float, (unsigned)h << 16);
}

// ---------------- projection via MFMA (X bf16 single, W bf16) ---------------
// W transpose+cast fused in: each block stages W[256][64] fp32 -> swizzled
// bf16 LDS [64 n][256 k] (L2-resident re-reads). Q pre-scaled by QSCALE.
__global__ __launch_bounds__(256) void proj_kernel(
    const float* __restrict__ Xq, const float* __restrict__ Xk, const float* __restrict__ Xv,
    const float* __restrict__ wq, const float* __restrict__ wk, const float* __restrict__ wv,
    ushort* __restrict__ Qb, ushort* __restrict__ Kb, ushort* __restrict__ Vtb)
{
    const float* X; const float* W;
    if (blockIdx.y == 0)      { X = Xq; W = wq; }
    else if (blockIdx.y == 1) { X = Xk; W = wk; }
    else                      { X = Xv; W = wv; }

    __shared__ __align__(16) char   WlsB[64 * 512];  // W^T bf16 [64 n][256 k], swizzled (32 KiB)
    __shared__ __align__(16) ushort Ob[64][64];      // output bounce (8 KiB)

    const int t    = threadIdx.x;
    const int lane = t & 63;
    const int w    = t >> 6;
    const int n    = lane & 15;
    const int g    = lane >> 4;
    const int row0 = blockIdx.x * 64;

    // ---- stage W^T bf16 into LDS (16B chunks swizzled: c ^= row&7, low 3b)
#pragma unroll
    for (int i = 0; i < 16; ++i) {
        int idx = t + i * 256;              // 0..4095 float4-quads
        int k   = idx >> 4;                 // 0..255
        int c4  = (idx & 15) * 4;           // 0,4,..,60 (output col group)
        float4 v = *reinterpret_cast<const float4*>(&W[(size_t)k * 64 + c4]);
        const float vv[4] = {v.x, v.y, v.z, v.w};
        const int cc = k >> 3;              // 16B chunk 0..31
        const int ke = (k & 7) * 2;         // byte within chunk
#pragma unroll
        for (int j = 0; j < 4; ++j) {
            int row = c4 + j;
            int cs  = (cc & 24) | ((cc ^ row) & 7);
            *reinterpret_cast<ushort*>(WlsB + row * 512 + cs * 16 + ke) = f2bf(vv[j]);
        }
    }
    __syncthreads();

    const float* xrow = X + (size_t)(row0 + 16 * w + n) * D_IN;

    f32x4 acc[4];
    const f32x4 zero4 = {0.f, 0.f, 0.f, 0.f};
#pragma unroll
    for (int nt = 0; nt < 4; ++nt) acc[nt] = zero4;

#pragma unroll
    for (int kt = 0; kt < 8; ++kt) {
        const float4 c0 = *reinterpret_cast<const float4*>(xrow + kt * 32 + 8 * g);
        const float4 c1 = *reinterpret_cast<const float4*>(xrow + kt * 32 + 8 * g + 4);
        L16 wb[4];
        const int cc = 4 * kt + g;          // chunk of k-range [kt*32+8g, +8)
#pragma unroll
        for (int nt = 0; nt < 4; ++nt) {
            const int row = 16 * nt + n;
            const int cs  = (cc & 24) | ((cc ^ row) & 7);
            wb[nt].i = *reinterpret_cast<const int4*>(WlsB + row * 512 + cs * 16);
        }

        const float xv[8] = {c0.x, c0.y, c0.z, c0.w, c1.x, c1.y, c1.z, c1.w};
        L16 xh;
#pragma unroll
        for (int i = 0; i < 8; ++i) xh.u[i] = f2bf(xv[i]);
#pragma unroll
        for (int nt = 0; nt < 4; ++nt)
            acc[nt] = __builtin_amdgcn_mfma_f32_16x16x32_bf16(xh.s, wb[nt].s, acc[nt], 0, 0, 0);
    }

    // epilogue: bounce through LDS for coalesced bf16 stores (V transposed)
    const bool isV = (blockIdx.y == 2);
    const float oscale = (blockIdx.y == 0) ? QSCALE : 1.0f;
    __syncthreads();                        // Wls reads done before Ob reuse? (separate bufs, but order waves)
#pragma unroll
    for (int j = 0; j < 4; ++j) {
#pragma unroll
        for (int nt = 0; nt < 4; ++nt) {
            ushort h = f2bf(acc[nt][j] * oscale);
            int r = 16 * w + 4 * g + j;     // m-row in block
            int c = 16 * nt + n;            // output column
            if (isV) Ob[c][r] = h; else Ob[r][c] = h;
        }
    }
    __syncthreads();
    const int b  = row0 >> 12;
    const int s0 = row0 & 4095;
#pragma unroll
    for (int i = 0; i < 2; ++i) {
        int idx = t + i * 256;              // 0..511
        int r = idx >> 3, c8 = (idx & 7) * 8;
        int4 v = *reinterpret_cast<const int4*>(&Ob[r][c8]);
        if (blockIdx.y == 0)
            *reinterpret_cast<int4*>(&Qb[(size_t)(row0 + r) * 64 + c8]) = v;
        else if (blockIdx.y == 1)
            *reinterpret_cast<int4*>(&Kb[(size_t)(row0 + r) * 64 + c8]) = v;
        else
            *reinterpret_cast<int4*>(&Vtb[((size_t)b * 64 + r) * S_LEN + s0 + c8]) = v;
    }
}

// ---------------- causal flash attention, swapped-QK bf16 MFMA, split-K -----
// BQ=256: 8 waves (512 thr) x 32 q-rows each; double-buffered K/V LDS, one
// barrier per tile; shuffle-free softmax; fused PV for both h-groups.
__global__ __launch_bounds__(512) void attn_kernel(
    const ushort* __restrict__ Q, const ushort* __restrict__ K,
    const ushort* __restrict__ Vt, float* __restrict__ O,
    ushort* __restrict__ Opart, float* __restrict__ Mpart, float* __restrict__ Lpart,
    int chunk_keys, int NCH, int lr4q, int Llive)
{
    __shared__ __align__(16) ushort Ks[2][64 * 64];    // K tiles, swizzled (2x8KB)
    __shared__ __align__(16) ushort Vs[2][64 * 64];    // V^T tiles, swizzled (2x8KB)
    __shared__ __align__(16) ushort Ps[8 * 16 * 64];   // per-wave P (2KB/wave, 16KB)

    const int Rq = 1 << lr4q;                    // chunk size in 256-row q-tile units

    // flat work item, chunk-major: off(c) = NQT*c - Rq*c*(c-1)/2
    const int b = blockIdx.x & 3;
    const int f = blockIdx.x >> 2;               // 0..Llive-1
    int c = 0;
    while (NQT * (c + 1) - ((Rq * (c + 1) * c) >> 1) <= f) ++c;   // <=16 iters
    const int off  = NQT * c - ((Rq * c * (c - 1)) >> 1);
    const int qt   = (NQT - 1) - (f - off);      // descending within chunk (LPT)
    const int ch   = c;
    const int q0   = qt * BQ;
    const int c0   = ch * chunk_keys;
    const int nchq = (qt >> lr4q) + 1;           // live chunks for this q-tile

    const int t    = threadIdx.x;
    const int lane = t & 63;
    const int w    = t >> 6;                     // 0..7
    const int n    = lane & 15;
    const int g    = lane >> 4;

    const int kend = (c0 + chunk_keys < q0 + BQ) ? c0 + chunk_keys : q0 + BQ;
    const int kt0  = c0 >> 6;
    const int kt1  = (kend + 63) >> 6;

    const ushort* Qp = Q  + (size_t)b * S_LEN * 64;
    const ushort* Kp = K  + (size_t)b * S_LEN * 64;
    const ushort* Vp = Vt + (size_t)b * 64 * S_LEN;

    char* PsB = (char*)Ps + w * 2048;

    const int wqmin = q0 + 32 * w;
    const int wqmax = wqmin + 31;

    // Q B-frags for both 16-col groups (col n of group h -> q-row wqmin+16h+n)
    L16 aq[2][2];
#pragma unroll
    for (int h = 0; h < 2; ++h) {
        const size_t qr = (size_t)(wqmin + 16 * h + n) * 64;
        aq[h][0].i = *reinterpret_cast<const int4*>(&Qp[qr + 8 * g]);
        aq[h][1].i = *reinterpret_cast<const int4*>(&Qp[qr + 32 + 8 * g]);
    }

    // all-ones A-frag for the MFMA row-sum (bf16 1.0 = 0x3F80)
    L16 ones;
    ones.i = make_int4(0x3F803F80, 0x3F803F80, 0x3F803F80, 0x3F803F80);

    f32x4 oacc[2][4];                            // oacc[h][nt][j] = O[qrow_h][16nt+4g+j]
    const f32x4 zero4 = {0.f, 0.f, 0.f, 0.f};
#pragma unroll
    for (int h = 0; h < 2; ++h)
#pragma unroll
        for (int nt = 0; nt < 4; ++nt) oacc[h][nt] = zero4;
    float mreg[2] = {-1e30f, -1e30f}, lreg[2] = {0.f, 0.f};

    const int srow = t >> 3, sc = t & 7;         // 512 thr: one row each (0..63)

    auto load_tile = [&](int4& kr, int4& vr, int kt_) {
        const int kk0 = kt_ << 6;
        kr = *reinterpret_cast<const int4*>(&Kp[(size_t)(kk0 + srow) * 64 + sc * 8]);
        vr = *reinterpret_cast<const int4*>(&Vp[(size_t)srow * S_LEN + kk0 + sc * 8]);
    };
    auto store_tile = [&](int buf, const int4& kr, const int4& vr) {
        char* kb = (char*)Ks + buf * 8192;
        char* vb = (char*)Vs + buf * 8192;
        *reinterpret_cast<int4*>(kb + SWZ(srow, sc)) = kr;
        *reinterpret_cast<int4*>(vb + SWZ(srow, sc)) = vr;
    };

    // prologue: stage tile kt0 into buf0; preload tile kt0+1 into regs
    int4 kv, vv;
    load_tile(kv, vv, kt0);
    store_tile(0, kv, vv);
    if (kt0 + 1 < kt1) load_tile(kv, vv, kt0 + 1);
    __syncthreads();

    int cur = 0;
    for (int kt = kt0; kt < kt1; ++kt) {
        const int k0 = kt << 6;
        // stage tile kt+1 into the other buffer; issue loads for kt+2
        if (kt + 1 < kt1) {
            store_tile(cur ^ 1, kv, vv);
            if (kt + 2 < kt1) load_tile(kv, vv, kt + 2);
        }

        if (k0 <= wqmax) {                       // compute (masked waves skip)
            char* KsB = (char*)Ks + cur * 8192;
            char* VsB = (char*)Vs + cur * 8192;

            // ---- QK^T swapped: A=K, B=Q. Lane holds S[key=k0+16t4+4g+j][qrow_h]
            f32x4 cS[2][4];
            __builtin_amdgcn_s_setprio(1);
#pragma unroll
            for (int t4 = 0; t4 < 4; ++t4) {
                L16 k0f, k1f;
                k0f.i = *reinterpret_cast<const int4*>(KsB + SWZ(16 * t4 + n, g));
                k1f.i = *reinterpret_cast<const int4*>(KsB + SWZ(16 * t4 + n, 4 + g));
#pragma unroll
                for (int h = 0; h < 2; ++h) {
                    f32x4 z = zero4;
                    z          = __builtin_amdgcn_mfma_f32_16x16x32_bf16(k0f.s, aq[h][0].s, z, 0, 0, 0);
                    cS[h][t4]  = __builtin_amdgcn_mfma_f32_16x16x32_bf16(k1f.s, aq[h][1].s, z, 0, 0, 0);
                }
            }
            __builtin_amdgcn_s_setprio(0);

            // ---- per group: mask + softmax + P-store + pa load (P buf reused)
            L16 pa[2][2];
#pragma unroll
            for (int h = 0; h < 2; ++h) {
                const int qrow = wqmin + 16 * h + n;
                float sc4[4][4];
#pragma unroll
                for (int t4 = 0; t4 < 4; ++t4)
#pragma unroll
                    for (int j = 0; j < 4; ++j) sc4[t4][j] = cS[h][t4][j];
                if (k0 + 63 > qrow) {
                    const int kb = k0 + 4 * g;
#pragma unroll
                    for (int t4 = 0; t4 < 4; ++t4)
#pragma unroll
                        for (int j = 0; j < 4; ++j)
                            if (kb + 16 * t4 + j > qrow) sc4[t4][j] = -1e30f;
                }

                // per-lane max of this lane's 16 scores (no cross-lane yet)
                float m0 = fmaxf(fmaxf(sc4[0][0], sc4[0][1]), fmaxf(sc4[0][2], sc4[0][3]));
                float m1 = fmaxf(fmaxf(sc4[1][0], sc4[1][1]), fmaxf(sc4[1][2], sc4[1][3]));
                float m2 = fmaxf(fmaxf(sc4[2][0], sc4[2][1]), fmaxf(sc4[2][2], sc4[2][3]));
                float m3 = fmaxf(fmaxf(sc4[3][0], sc4[3][1]), fmaxf(sc4[3][2], sc4[3][3]));
                const float lmax = fmaxf(fmaxf(m0, m1), fmaxf(m2, m3));

                // defer-max: full cross-lane reduce ONLY when a row grew > 8
                if (__any(lmax > mreg[h] + 8.f)) {
                    float mx = lmax;
                    mx = fmaxf(mx, __shfl_xor(mx, 16, 64));
                    mx = fmaxf(mx, __shfl_xor(mx, 32, 64));
                    const float mnew  = fmaxf(mreg[h], mx);
                    const float alpha = exp2f(mreg[h] - mnew);
                    mreg[h] = mnew;
                    lreg[h] *= alpha;
#pragma unroll
                    for (int nt = 0; nt < 4; ++nt)
#pragma unroll
                        for (int j = 0; j < 4; ++j) oacc[h][nt][j] *= alpha;
                }

#pragma unroll
                for (int t4 = 0; t4 < 4; ++t4) {
                    U8 pw;
#pragma unroll
                    for (int j = 0; j < 4; ++j)
                        pw.u[j] = f2bf_t(exp2f(sc4[t4][j] - mreg[h]));
                    *reinterpret_cast<uint2*>(PsB + SWZ(n, 2 * t4 + (g >> 1)) + 8 * (g & 1)) = pw.d;
                }
                // drain this h's P writes, pull its A-frags into regs, l-sum
                asm volatile("s_waitcnt lgkmcnt(0)" ::: "memory");
                pa[h][0].i = *reinterpret_cast<const int4*>(PsB + SWZ(n, g));
                pa[h][1].i = *reinterpret_cast<const int4*>(PsB + SWZ(n, 4 + g));
                f32x4 ls = zero4;
                ls = __builtin_amdgcn_mfma_f32_16x16x32_bf16(ones.s, pa[h][0].s, ls, 0, 0, 0);
                ls = __builtin_amdgcn_mfma_f32_16x16x32_bf16(ones.s, pa[h][1].s, ls, 0, 0, 0);
                lreg[h] += ls[0];                // all D-rows equal the column sum
            }

            // ---- fused PV for both h: shared bv loads, one 16-MFMA cluster
            __builtin_amdgcn_s_setprio(1);
#pragma unroll
            for (int nt = 0; nt < 4; ++nt) {
                L16 bv0, bv1;
                bv0.i = *reinterpret_cast<const int4*>(VsB + SWZ(16 * nt + n, g));
                bv1.i = *reinterpret_cast<const int4*>(VsB + SWZ(16 * nt + n, 4 + g));
                oacc[0][nt] = __builtin_amdgcn_mfma_f32_16x16x32_bf16(bv0.s, pa[0][0].s, oacc[0][nt], 0, 0, 0);
                oacc[0][nt] = __builtin_amdgcn_mfma_f32_16x16x32_bf16(bv1.s, pa[0][1].s, oacc[0][nt], 0, 0, 0);
                oacc[1][nt] = __builtin_amdgcn_mfma_f32_16x16x32_bf16(bv0.s, pa[1][0].s, oacc[1][nt], 0, 0, 0);
                oacc[1][nt] = __builtin_amdgcn_mfma_f32_16x16x32_bf16(bv1.s, pa[1][1].s, oacc[1][nt], 0, 0, 0);
            }
            __builtin_amdgcn_s_setprio(0);
        }
        __syncthreads();                         // one barrier per tile
        cur ^= 1;
    }

    if (nchq == 1) {
        // direct normalized write (qt < Rq), scattered 4B stores
#pragma unroll
        for (int h = 0; h < 2; ++h) {
            const float inv = 1.f / lreg[h];
            float* orow = O + ((size_t)b * S_LEN + wqmin + 16 * h + n) * 64;
#pragma unroll
            for (int nt = 0; nt < 4; ++nt)
#pragma unroll
                for (int j = 0; j < 4; ++j)
                    orow[16 * nt + 4 * g + j] = oacc[h][nt][j] * inv;
        }
    } else {
        // bf16 partials in swizzled byte order (reduce de-swizzles), per h
        const size_t slot = (size_t)((qt << 2) | b) * NCH + ch;
#pragma unroll
        for (int h = 0; h < 2; ++h) {
#pragma unroll
            for (int nt = 0; nt < 4; ++nt) {
                U8 pw;
#pragma unroll
                for (int j = 0; j < 4; ++j) pw.u[j] = f2bf(oacc[h][nt][j]);
                *reinterpret_cast<uint2*>(PsB + SWZ(n, 2 * nt + (g >> 1)) + 8 * (g & 1)) = pw.d;
            }
            asm volatile("s_waitcnt lgkmcnt(0)" ::: "memory");
            ushort* dst = Opart + slot * (BQ * 64) + w * 2048 + h * 1024;
#pragma unroll
            for (int i = 0; i < 2; ++i) {
                int ii = i * 64 + lane;
                *reinterpret_cast<int4*>(dst + ii * 8) =
                    *reinterpret_cast<const int4*>((const char*)PsB + ii * 16);
            }
        }
        if (g == 0) {
#pragma unroll
            for (int h = 0; h < 2; ++h) {
                Mpart[slot * BQ + 32 * w + 16 * h + n] = mreg[h];
                Lpart[slot * BQ + 32 * w + 16 * h + n] = lreg[h];
            }
        }
    }
}

// ---------------- split-K combine (bf16 partials, log2-domain m) ------------
// 8 blocks per (b,qt): seg = 32-row segment. 8 threads/row x 8 floats.
__global__ __launch_bounds__(256) void reduce_kernel(
    const ushort* __restrict__ Opart, const float* __restrict__ Mpart,
    const float* __restrict__ Lpart, float* __restrict__ O,
    int NCH, int chunk_keys)
{
    const int bx  = blockIdx.x >> 3;     // (qt<<2)|b
    const int seg = blockIdx.x & 7;      // 32-row segment of the 256-row q-tile
    const int b   = bx & 3;
    const int qt  = bx >> 2;
    const int q0  = qt * BQ;
    const int nch = (q0 + BQ + chunk_keys - 1) / chunk_keys;
    if (nch <= 1) return;               // attn wrote O directly

    const int t    = threadIdx.x;
    const int row  = seg * 32 + (t >> 3);   // 0..255
    const int c8   = t & 7;                 // 16B chunk within the row
    const int wv   = row >> 5, rl = row & 31;
    const int cswz = (c8 ^ (rl & 7)) << 4;  // de-swizzle

    const size_t mbase = (size_t)bx * NCH * BQ + row;
    float mmax = -1e30f;
#pragma unroll 4
    for (int ch = 0; ch < nch; ++ch)
        mmax = fmaxf(mmax, Mpart[mbase + (size_t)ch * BQ]);

    float ltot = 0.f;
    float acc[8];
#pragma unroll
    for (int i = 0; i < 8; ++i) acc[i] = 0.f;

#pragma unroll 4
    for (int ch = 0; ch < nch; ++ch) {
        const float wgt = exp2f(Mpart[mbase + (size_t)ch * BQ] - mmax);
        ltot += wgt * Lpart[mbase + (size_t)ch * BQ];
        const char* ob = (const char*)(Opart + ((size_t)bx * NCH + ch) * (BQ * 64))
                         + wv * 4096 + rl * 128 + cswz;
        L16 v;
        v.i = *reinterpret_cast<const int4*>(ob);
#pragma unroll
        for (int i = 0; i < 8; ++i) acc[i] += wgt * bf2f(v.u[i]);
    }
    const float inv = 1.f / ltot;
    float* dst = O + ((size_t)b * S_LEN + q0 + row) * 64 + c8 * 8;
#pragma unroll
    for (int i = 0; i < 2; ++i) {
        float4 o = make_float4(acc[4 * i] * inv, acc[4 * i + 1] * inv,
                               acc[4 * i + 2] * inv, acc[4 * i + 3] * inv);
        *reinterpret_cast<float4*>(dst + i * 4) = o;
    }
}

extern "C" void kernel_launch(void* const* d_in, const int* in_sizes, int n_in,
                              void* d_out, int out_size, void* d_ws, size_t ws_size,
                              hipStream_t stream) {
    // setup_inputs() order: keys-X, values-X, queries-X, wq, wk, wv
    const float* Xk = (const float*)d_in[0];
    const float* Xv = (const float*)d_in[1];
    const float* Xq = (const float*)d_in[2];
    const float* wq = (const float*)d_in[3];
    const float* wk = (const float*)d_in[4];
    const float* wv = (const float*)d_in[5];
    float* out = (float*)d_out;

    const size_t NEL = (size_t)BATCH * S_LEN * D_OUT;   // 1,048,576
    ushort* Qb  = (ushort*)d_ws;
    ushort* Kb  = Qb + NEL;
    ushort* Vtb = Kb + NEL;
    const size_t base_bytes = 3 * NEL * sizeof(ushort);               // 6,291,456
    const size_t per_nch    = (size_t)BATCH * NQT *
                              (BQ * 64 * sizeof(ushort) + 2 * BQ * sizeof(float));

    int NCH = 1;
    if      (ws_size >= base_bytes + 16 * per_nch) NCH = 16;
    else if (ws_size >= base_bytes +  8 * per_nch) NCH = 8;
    else if (ws_size >= base_bytes +  4 * per_nch) NCH = 4;
    else if (ws_size >= base_bytes +  2 * per_nch) NCH = 2;
    const int chunk_keys = S_LEN / NCH;                 // NCH=16 -> 256 = BQ
    const int Rq = chunk_keys / BQ;                     // chunk in 256-row q-tiles
    int lr4q = 0; while ((1 << lr4q) < Rq) ++lr4q;      // log2(Rq)
    const int Llive = NCH * NQT - Rq * ((NCH * (NCH - 1)) >> 1);

    ushort* Opart = (ushort*)((char*)d_ws + base_bytes);
    float*  Mpart = (float*)((char*)d_ws + base_bytes +
                             (size_t)BATCH * NQT * NCH * BQ * 64 * sizeof(ushort));
    float*  Lpart = Mpart + (size_t)BATCH * NQT * NCH * BQ;

    proj_kernel<<<dim3(BATCH * S_LEN / 64, 3), 256, 0, stream>>>(
        Xq, Xk, Xv, wq, wk, wv, Qb, Kb, Vtb);

    attn_kernel<<<4 * Llive, 512, 0, stream>>>(Qb, Kb, Vtb, out, Opart, Mpart, Lpart,
                                               chunk_keys, NCH, lr4q, Llive);
    if (NCH > 1)
        reduce_kernel<<<BATCH * NQT * 8, 256, 0, stream>>>(Opart, Mpart, Lpart, out,
                                                           NCH, chunk_keys);
}